// Round 3
// baseline (563.010 us; speedup 1.0000x reference)
//
#include <hip/hip_runtime.h>
#include <math.h>

#define NRAYS 8192
#define XPAD 72   // bf16 per LDS activation row: 64 + 8 pad (144 B, 16B-aligned)

typedef short s16x8 __attribute__((ext_vector_type(8)));
typedef float f32x4 __attribute__((ext_vector_type(4)));

__device__ __forceinline__ unsigned short f2bf(float x){
  unsigned u = __float_as_uint(x);
  u += 0x7FFF + ((u >> 16) & 1);           // RNE
  return (unsigned short)(u >> 16);
}
__device__ __forceinline__ float bf2f(unsigned short s){ return __uint_as_float(((unsigned)s) << 16); }
__device__ __forceinline__ float softplusf_(float x){ return (x > 20.f) ? x : log1pf(expf(x)); }
__device__ __forceinline__ float sigmoidf_(float x){ return 1.f / (1.f + expf(-x)); }

// d_ws layout (ushort elements): WT1[64][32] @0, WT2[64][64] @2048, WO1[64][64] @6144, WC1[64][64] @10240
__global__ void prep_weights(const float* __restrict__ Wt1, const float* __restrict__ Wt2,
                             const float* __restrict__ Wo1, const float* __restrict__ Wc1,
                             unsigned short* __restrict__ ws)
{
  const int i0 = blockIdx.x * blockDim.x + threadIdx.x;
  const int st = gridDim.x * blockDim.x;
  for (int i = i0; i < 2048; i += st){ int n = i >> 5, k = i & 31; ws[i]         = f2bf(Wt1[k * 64 + n]); }
  for (int i = i0; i < 4096; i += st){ int n = i >> 6, k = i & 63; ws[2048 + i]  = f2bf(Wt2[k * 64 + n]); }
  for (int i = i0; i < 4096; i += st){ int n = i >> 6, k = i & 63; ws[6144 + i]  = f2bf(Wo1[k * 64 + n]); }
  for (int i = i0; i < 4096; i += st){ int n = i >> 6, k = i & 63; ws[10240 + i] = f2bf(Wc1[k * 64 + n]); }
}

// K=64 layer: acc[mt][nt] = bias + A @ W. A frags a[mt][ks]; WT[n][k] bf16 rows of 64.
__device__ __forceinline__ void layer64(const s16x8 a[4][2], const unsigned short* __restrict__ wt,
                                        const float* __restrict__ bias, int ln15, int quad,
                                        f32x4 acc[4][4])
{
  float bv[4];
#pragma unroll
  for (int nt = 0; nt < 4; ++nt) bv[nt] = bias[nt * 16 + ln15];
#pragma unroll
  for (int mt = 0; mt < 4; ++mt)
#pragma unroll
    for (int nt = 0; nt < 4; ++nt){ f32x4 c; c[0] = bv[nt]; c[1] = bv[nt]; c[2] = bv[nt]; c[3] = bv[nt]; acc[mt][nt] = c; }
#pragma unroll
  for (int ks = 0; ks < 2; ++ks){
    s16x8 b[4];
#pragma unroll
    for (int nt = 0; nt < 4; ++nt)
      b[nt] = *(const s16x8*)(wt + (nt * 16 + ln15) * 64 + ks * 32 + quad * 8);
#pragma unroll
    for (int mt = 0; mt < 4; ++mt)
#pragma unroll
      for (int nt = 0; nt < 4; ++nt)
        acc[mt][nt] = __builtin_amdgcn_mfma_f32_16x16x32_bf16(a[mt][ks], b[nt], acc[mt][nt], 0, 0, 0);
  }
}

// relu + bf16 + scatter D tiles back to X rows (wave-local rows)
__device__ __forceinline__ void store_relu(unsigned short* __restrict__ sX, int wrow, int ln15, int quad,
                                           const f32x4 acc[4][4])
{
#pragma unroll
  for (int mt = 0; mt < 4; ++mt){
    const int rowb = wrow + mt * 16 + quad * 4;
#pragma unroll
    for (int nt = 0; nt < 4; ++nt){
      const int col = nt * 16 + ln15;
#pragma unroll
      for (int r = 0; r < 4; ++r)
        sX[(rowb + r) * XPAD + col] = f2bf(fmaxf(acc[mt][nt][r], 0.f));
    }
  }
}

extern "C" __global__ __launch_bounds__(256, 4)
void lightplane_fwd(const float* __restrict__ origins, const float* __restrict__ dirs,
                    const float* __restrict__ nearv,   const float* __restrict__ farv,
                    const float* __restrict__ grid,
                    const float* __restrict__ Wr,  const float* __restrict__ br,
                    const float* __restrict__ bt1, const float* __restrict__ bt2,
                    const float* __restrict__ bo1,
                    const float* __restrict__ Wo2, const float* __restrict__ bo2,
                    const float* __restrict__ bc1,
                    const float* __restrict__ Wc2, const float* __restrict__ bc2,
                    const unsigned short* __restrict__ ws,
                    float* __restrict__ out)
{
  __shared__ unsigned short s_X[256 * XPAD];   // 36864 B
  __shared__ float s_enc[2][64];
  __shared__ float s_part[2][2][4];
  __shared__ float s_wtot[4];

  const int tid   = threadIdx.x;
  const int lane  = tid & 63;
  const int wv    = tid >> 6;
  const int ln15  = lane & 15, quad = lane >> 4;
  const int wrow  = wv * 64;
  const int r_loc = tid >> 7;
  const int s_idx = tid & 127;
  const int ray   = blockIdx.x * 2 + r_loc;   // random (input) ray order: best HBM channel spread

  // ---- sample point ----
  const float dx = dirs[ray * 3 + 0], dy = dirs[ray * 3 + 1], dz = dirs[ray * 3 + 2];
  const float ox = origins[ray * 3 + 0], oy = origins[ray * 3 + 1], oz = origins[ray * 3 + 2];
  const float nr = nearv[ray], fa = farv[ray];
  const float t  = nr + (fa - nr) * ((s_idx + 0.5f) * (1.0f / 128.0f));
  const float px = fmaf(t, dx, ox), py = fmaf(t, dy, oy), pz = fmaf(t, dz, oz);

  const float cx = (px + 1.f) * 63.5f, cy = (py + 1.f) * 63.5f, cz = (pz + 1.f) * 63.5f;
  const float fx0 = floorf(cx), fy0 = floorf(cy), fz0 = floorf(cz);
  const float frx = cx - fx0, fry = cy - fy0, frz = cz - fz0;
  int ix0 = min(max((int)fx0, 0), 127), iy0 = min(max((int)fy0, 0), 127), iz0 = min(max((int)fz0, 0), 127);
  int ix1 = min(ix0 + 1, 127), iy1 = min(iy0 + 1, 127), iz1 = min(iz0 + 1, 127);
  const float wxs[2] = {1.f - frx, frx}, wys[2] = {1.f - fry, fry}, wzs[2] = {1.f - frz, frz};
  const int xi[2] = {ix0, ix1}, yi[2] = {iy0, iy1}, zi[2] = {iz0, iz1};

  // 8 corner byte-offsets + weights (all indices compile-time after unroll -> registers)
  int  coff[8];
  float cw[8];
#pragma unroll
  for (int zz = 0; zz < 2; ++zz)
#pragma unroll
    for (int yy = 0; yy < 2; ++yy)
#pragma unroll
      for (int xx = 0; xx < 2; ++xx) {
        const int c = zz * 4 + yy * 2 + xx;
        coff[c] = ((zi[zz] * 128 + yi[yy]) * 128 + xi[xx]) * 128;   // bytes (32 ch * 4 B)
        cw[c]   = wzs[zz] * wys[yy] * wxs[xx];
      }
  const char* __restrict__ gbase = (const char*)grid;

  // ---- gather, channel-chunk-major: phase q loads chunk q of ALL 8 corners ----
  // (first phase issues 8 independent line-misses in parallel; later phases hit L1/MSHR)
#pragma unroll
  for (int qp = 0; qp < 4; ++qp) {
    s16x8 pk;
#pragma unroll
    for (int h = 0; h < 2; ++h) {
      const int q = qp * 2 + h;
      float4 v[8];
#pragma unroll
      for (int c = 0; c < 8; ++c)
        v[c] = *(const float4*)(gbase + coff[c] + q * 16);
      float f0 = 0.f, f1 = 0.f, f2 = 0.f, f3 = 0.f;
#pragma unroll
      for (int c = 0; c < 8; ++c) {
        f0 = fmaf(cw[c], v[c].x, f0);
        f1 = fmaf(cw[c], v[c].y, f1);
        f2 = fmaf(cw[c], v[c].z, f2);
        f3 = fmaf(cw[c], v[c].w, f3);
      }
      pk[h * 4 + 0] = (short)f2bf(f0);
      pk[h * 4 + 1] = (short)f2bf(f1);
      pk[h * 4 + 2] = (short)f2bf(f2);
      pk[h * 4 + 3] = (short)f2bf(f3);
    }
    *(s16x8*)&s_X[tid * XPAD + qp * 8] = pk;   // wave-local rows; no barrier needed
  }

  // ---- per-ray harmonic encoding @ Wr + br (f32, threads 0..127) ----
  // after the gather so the global loads issue at kernel entry
  if (tid < 128) {
    const int rr = tid >> 6, j = tid & 63;
    const int rg = blockIdx.x * 2 + rr;
    const float ddx = dirs[rg * 3 + 0], ddy = dirs[rg * 3 + 1], ddz = dirs[rg * 3 + 2];
    float h[21]; float f = 1.f;
#pragma unroll
    for (int q = 0; q < 3; ++q) {
      h[q * 3 + 0] = sinf(ddx * f); h[q * 3 + 1] = sinf(ddy * f); h[q * 3 + 2] = sinf(ddz * f);
      h[9 + q * 3 + 0] = cosf(ddx * f); h[9 + q * 3 + 1] = cosf(ddy * f); h[9 + q * 3 + 2] = cosf(ddz * f);
      f *= 2.f;
    }
    h[18] = ddx; h[19] = ddy; h[20] = ddz;
    float a = br[j];
#pragma unroll
    for (int i = 0; i < 21; ++i) a = fmaf(h[i], Wr[i * 64 + j], a);
    s_enc[rr][j] = a;
  }

  f32x4 acc[4][4];

  // ---- T1: 32 -> 64 (K=32, one k-step) ----
  {
    s16x8 a1[4];
#pragma unroll
    for (int mt = 0; mt < 4; ++mt)
      a1[mt] = *(const s16x8*)&s_X[(wrow + mt * 16 + ln15) * XPAD + quad * 8];
    float bv[4];
#pragma unroll
    for (int nt = 0; nt < 4; ++nt) bv[nt] = bt1[nt * 16 + ln15];
#pragma unroll
    for (int mt = 0; mt < 4; ++mt)
#pragma unroll
      for (int nt = 0; nt < 4; ++nt){ f32x4 c; c[0]=bv[nt];c[1]=bv[nt];c[2]=bv[nt];c[3]=bv[nt]; acc[mt][nt]=c; }
    s16x8 b[4];
#pragma unroll
    for (int nt = 0; nt < 4; ++nt)
      b[nt] = *(const s16x8*)(ws + (nt * 16 + ln15) * 32 + quad * 8);
#pragma unroll
    for (int mt = 0; mt < 4; ++mt)
#pragma unroll
      for (int nt = 0; nt < 4; ++nt)
        acc[mt][nt] = __builtin_amdgcn_mfma_f32_16x16x32_bf16(a1[mt], b[nt], acc[mt][nt], 0, 0, 0);
    store_relu(s_X, wrow, ln15, quad, acc);
  }

  // ---- T2: 64 -> 64 -> e ----
  {
    s16x8 a[4][2];
#pragma unroll
    for (int ks = 0; ks < 2; ++ks)
#pragma unroll
      for (int mt = 0; mt < 4; ++mt)
        a[mt][ks] = *(const s16x8*)&s_X[(wrow + mt * 16 + ln15) * XPAD + ks * 32 + quad * 8];
    layer64(a, ws + 2048, bt2, ln15, quad, acc);
    store_relu(s_X, wrow, ln15, quad, acc);   // X = e
  }

  // ---- keep e fragments in registers (A-operand layout) ----
  s16x8 ea[4][2];
#pragma unroll
  for (int ks = 0; ks < 2; ++ks)
#pragma unroll
    for (int mt = 0; mt < 4; ++mt)
      ea[mt][ks] = *(const s16x8*)&s_X[(wrow + mt * 16 + ln15) * XPAD + ks * 32 + quad * 8];

  // ---- opacity: relu(e@Wo1+bo1) -> X, then per-thread dot with Wo2 ----
  layer64(ea, ws + 6144, bo1, ln15, quad, acc);
  store_relu(s_X, wrow, ln15, quad, acc);
  float raw = bo2[0];
#pragma unroll
  for (int q = 0; q < 8; ++q) {
    s16x8 v = *(const s16x8*)&s_X[tid * XPAD + q * 8];
#pragma unroll
    for (int j = 0; j < 8; ++j)
      raw = fmaf(bf2f((unsigned short)v[j]), Wo2[q * 8 + j], raw);
  }
  const float density = softplusf_(raw);
  const float delta   = (fa - nr) * (1.0f / 128.0f);
  const float alpha   = 1.f - expf(-delta * density);

  __syncthreads();   // s_enc (cross-wave) ready

  // ---- color: cin-frags = e-frags + enc (enc varies only along k => per-wave broadcast frag) ----
  {
    s16x8 a[4][2];
#pragma unroll
    for (int ks = 0; ks < 2; ++ks) {
      const float* ep = &s_enc[r_loc][ks * 32 + quad * 8];
      float4 e0 = *(const float4*)ep;
      float4 e1 = *(const float4*)(ep + 4);
      float encv[8] = {e0.x, e0.y, e0.z, e0.w, e1.x, e1.y, e1.z, e1.w};
#pragma unroll
      for (int mt = 0; mt < 4; ++mt) {
        s16x8 v;
#pragma unroll
        for (int j = 0; j < 8; ++j)
          v[j] = (short)f2bf(bf2f((unsigned short)ea[mt][ks][j]) + encv[j]);
        a[mt][ks] = v;
      }
    }
    layer64(a, ws + 10240, bc1, ln15, quad, acc);
    store_relu(s_X, wrow, ln15, quad, acc);
  }
  float c0 = bc2[0], c1 = bc2[1], c2 = bc2[2];
#pragma unroll
  for (int q = 0; q < 8; ++q) {
    s16x8 v = *(const s16x8*)&s_X[tid * XPAD + q * 8];
#pragma unroll
    for (int j = 0; j < 8; ++j) {
      const float h = bf2f((unsigned short)v[j]);
      c0 = fmaf(h, Wc2[(q * 8 + j) * 3 + 0], c0);
      c1 = fmaf(h, Wc2[(q * 8 + j) * 3 + 1], c1);
      c2 = fmaf(h, Wc2[(q * 8 + j) * 3 + 2], c2);
    }
  }
  c0 = sigmoidf_(c0); c1 = sigmoidf_(c1); c2 = sigmoidf_(c2);

  // ---- transmittance: per-wave shfl scan (6 steps, no barriers) + cross-wave prefix ----
  float sc = 1.f - alpha;
#pragma unroll
  for (int off = 1; off < 64; off <<= 1) {
    const float u = __shfl_up(sc, off, 64);
    if (lane >= off) sc *= u;
  }
  float excl = __shfl_up(sc, 1, 64);
  if (lane == 0) excl = 1.f;
  if (lane == 63) s_wtot[wv] = sc;
  __syncthreads();
  const int w_in_ray = s_idx >> 6;                       // 0 or 1 within the ray
  const float prefix = w_in_ray ? s_wtot[r_loc * 2] : 1.f;
  const float wgt = prefix * excl * alpha;

  // ---- color integral ----
  float p0 = wgt * c0, p1 = wgt * c1, p2 = wgt * c2;
#pragma unroll
  for (int off = 32; off > 0; off >>= 1) {
    p0 += __shfl_down(p0, off, 64);
    p1 += __shfl_down(p1, off, 64);
    p2 += __shfl_down(p2, off, 64);
  }
  if (lane == 0) {
    s_part[r_loc][w_in_ray][0] = p0; s_part[r_loc][w_in_ray][1] = p1; s_part[r_loc][w_in_ray][2] = p2;
  }
  __syncthreads();
  if (s_idx == 0) {
    out[ray * 3 + 0] = s_part[r_loc][0][0] + s_part[r_loc][1][0];
    out[ray * 3 + 1] = s_part[r_loc][0][1] + s_part[r_loc][1][1];
    out[ray * 3 + 2] = s_part[r_loc][0][2] + s_part[r_loc][1][2];
    out[NRAYS * 3 + ray] = 1.f - s_wtot[r_loc * 2] * s_wtot[r_loc * 2 + 1];
  }
}

extern "C" void kernel_launch(void* const* d_in, const int* in_sizes, int n_in,
                              void* d_out, int out_size, void* d_ws, size_t ws_size,
                              hipStream_t stream)
{
  (void)in_sizes; (void)n_in; (void)out_size; (void)ws_size;
  const float* origins = (const float*)d_in[0];
  const float* dirs    = (const float*)d_in[1];
  const float* nearv   = (const float*)d_in[2];
  const float* farv    = (const float*)d_in[3];
  const float* grid    = (const float*)d_in[4];
  const float* Wr  = (const float*)d_in[5];
  const float* br  = (const float*)d_in[6];
  const float* Wt1 = (const float*)d_in[7];
  const float* bt1 = (const float*)d_in[8];
  const float* Wt2 = (const float*)d_in[9];
  const float* bt2 = (const float*)d_in[10];
  const float* Wo1 = (const float*)d_in[11];
  const float* bo1 = (const float*)d_in[12];
  const float* Wo2 = (const float*)d_in[13];
  const float* bo2 = (const float*)d_in[14];
  const float* Wc1 = (const float*)d_in[15];
  const float* bc1 = (const float*)d_in[16];
  const float* Wc2 = (const float*)d_in[17];
  const float* bc2 = (const float*)d_in[18];
  unsigned short* ws = (unsigned short*)d_ws;
  float* out = (float*)d_out;

  prep_weights<<<16, 256, 0, stream>>>(Wt1, Wt2, Wo1, Wc1, ws);
  lightplane_fwd<<<NRAYS / 2, 256, 0, stream>>>(origins, dirs, nearv, farv, grid,
                                                Wr, br, bt1, bt2, bo1, Wo2, bo2,
                                                bc1, Wc2, bc2, ws, out);
}

// Round 4
// 510.287 us; speedup vs baseline: 1.1033x; 1.1033x over previous
//
#include <hip/hip_runtime.h>
#include <math.h>

#define NRAYS 8192
#define XPAD 72   // bf16 per LDS activation row: 64 + 8 pad (144 B, 16B-aligned)

typedef short s16x8 __attribute__((ext_vector_type(8)));
typedef float f32x4 __attribute__((ext_vector_type(4)));

__device__ __forceinline__ unsigned short f2bf(float x){
  unsigned u = __float_as_uint(x);
  u += 0x7FFF + ((u >> 16) & 1);           // RNE
  return (unsigned short)(u >> 16);
}
__device__ __forceinline__ float bf2f(unsigned short s){ return __uint_as_float(((unsigned)s) << 16); }
__device__ __forceinline__ float softplusf_(float x){ return (x > 20.f) ? x : log1pf(expf(x)); }
__device__ __forceinline__ float sigmoidf_(float x){ return 1.f / (1.f + expf(-x)); }

// d_ws layout (ushort elements): WT1[64][32] @0, WT2[64][64] @2048, WO1[64][64] @6144, WC1[64][64] @10240
__global__ void prep_weights(const float* __restrict__ Wt1, const float* __restrict__ Wt2,
                             const float* __restrict__ Wo1, const float* __restrict__ Wc1,
                             unsigned short* __restrict__ ws)
{
  const int i0 = blockIdx.x * blockDim.x + threadIdx.x;
  const int st = gridDim.x * blockDim.x;
  for (int i = i0; i < 2048; i += st){ int n = i >> 5, k = i & 31; ws[i]         = f2bf(Wt1[k * 64 + n]); }
  for (int i = i0; i < 4096; i += st){ int n = i >> 6, k = i & 63; ws[2048 + i]  = f2bf(Wt2[k * 64 + n]); }
  for (int i = i0; i < 4096; i += st){ int n = i >> 6, k = i & 63; ws[6144 + i]  = f2bf(Wo1[k * 64 + n]); }
  for (int i = i0; i < 4096; i += st){ int n = i >> 6, k = i & 63; ws[10240 + i] = f2bf(Wc1[k * 64 + n]); }
}

// K=64 layer: acc[mt][nt] = bias + A @ W. A frags a[mt][ks]; WT[n][k] bf16 rows of 64.
__device__ __forceinline__ void layer64(const s16x8 a[4][2], const unsigned short* __restrict__ wt,
                                        const float* __restrict__ bias, int ln15, int quad,
                                        f32x4 acc[4][4])
{
  float bv[4];
#pragma unroll
  for (int nt = 0; nt < 4; ++nt) bv[nt] = bias[nt * 16 + ln15];
#pragma unroll
  for (int mt = 0; mt < 4; ++mt)
#pragma unroll
    for (int nt = 0; nt < 4; ++nt){ f32x4 c; c[0] = bv[nt]; c[1] = bv[nt]; c[2] = bv[nt]; c[3] = bv[nt]; acc[mt][nt] = c; }
#pragma unroll
  for (int ks = 0; ks < 2; ++ks){
    s16x8 b[4];
#pragma unroll
    for (int nt = 0; nt < 4; ++nt)
      b[nt] = *(const s16x8*)(wt + (nt * 16 + ln15) * 64 + ks * 32 + quad * 8);
#pragma unroll
    for (int mt = 0; mt < 4; ++mt)
#pragma unroll
      for (int nt = 0; nt < 4; ++nt)
        acc[mt][nt] = __builtin_amdgcn_mfma_f32_16x16x32_bf16(a[mt][ks], b[nt], acc[mt][nt], 0, 0, 0);
  }
}

// relu + bf16 + scatter D tiles back to X rows (wave-local rows)
__device__ __forceinline__ void store_relu(unsigned short* __restrict__ sX, int wrow, int ln15, int quad,
                                           const f32x4 acc[4][4])
{
#pragma unroll
  for (int mt = 0; mt < 4; ++mt){
    const int rowb = wrow + mt * 16 + quad * 4;
#pragma unroll
    for (int nt = 0; nt < 4; ++nt){
      const int col = nt * 16 + ln15;
#pragma unroll
      for (int r = 0; r < 4; ++r)
        sX[(rowb + r) * XPAD + col] = f2bf(fmaxf(acc[mt][nt][r], 0.f));
    }
  }
}

// launch_bounds(256,3): per-SIMD reg pool = 512; this kernel needs ~144 (80 VGPR + 64 AGPR)
// -> 3 waves/SIMD spill-free. Demanding 4 (R1-R3) forced a 128-reg budget and ~300 MB/dispatch
// of scratch spill traffic (WRITE_SIZE 151-174 MB on a kernel that writes 130 KB).
extern "C" __global__ __launch_bounds__(256, 3)
void lightplane_fwd(const float* __restrict__ origins, const float* __restrict__ dirs,
                    const float* __restrict__ nearv,   const float* __restrict__ farv,
                    const float* __restrict__ grid,
                    const float* __restrict__ Wr,  const float* __restrict__ br,
                    const float* __restrict__ bt1, const float* __restrict__ bt2,
                    const float* __restrict__ bo1,
                    const float* __restrict__ Wo2, const float* __restrict__ bo2,
                    const float* __restrict__ bc1,
                    const float* __restrict__ Wc2, const float* __restrict__ bc2,
                    const unsigned short* __restrict__ ws,
                    float* __restrict__ out)
{
  __shared__ unsigned short s_X[256 * XPAD];   // 36864 B
  __shared__ float s_enc[2][64];
  __shared__ float s_part[2][2][4];
  __shared__ float s_wtot[4];

  const int tid   = threadIdx.x;
  const int lane  = tid & 63;
  const int wv    = tid >> 6;
  const int ln15  = lane & 15, quad = lane >> 4;
  const int wrow  = wv * 64;
  const int r_loc = tid >> 7;
  const int s_idx = tid & 127;
  const int ray   = blockIdx.x * 2 + r_loc;   // random (input) ray order: best HBM channel spread

  // ---- sample point ----
  const float dx = dirs[ray * 3 + 0], dy = dirs[ray * 3 + 1], dz = dirs[ray * 3 + 2];
  const float ox = origins[ray * 3 + 0], oy = origins[ray * 3 + 1], oz = origins[ray * 3 + 2];
  const float nr = nearv[ray], fa = farv[ray];
  const float t  = nr + (fa - nr) * ((s_idx + 0.5f) * (1.0f / 128.0f));
  const float px = fmaf(t, dx, ox), py = fmaf(t, dy, oy), pz = fmaf(t, dz, oz);

  const float cx = (px + 1.f) * 63.5f, cy = (py + 1.f) * 63.5f, cz = (pz + 1.f) * 63.5f;
  const float fx0 = floorf(cx), fy0 = floorf(cy), fz0 = floorf(cz);
  const float frx = cx - fx0, fry = cy - fy0, frz = cz - fz0;
  int ix0 = min(max((int)fx0, 0), 127), iy0 = min(max((int)fy0, 0), 127), iz0 = min(max((int)fz0, 0), 127);
  int ix1 = min(ix0 + 1, 127), iy1 = min(iy0 + 1, 127), iz1 = min(iz0 + 1, 127);
  const float wxs[2] = {1.f - frx, frx}, wys[2] = {1.f - fry, fry}, wzs[2] = {1.f - frz, frz};
  const int xi[2] = {ix0, ix1}, yi[2] = {iy0, iy1}, zi[2] = {iz0, iz1};

  // 8 corner byte-offsets + weights (each corner = one aligned 128-B line)
  int  coff[8];
  float cw[8];
#pragma unroll
  for (int zz = 0; zz < 2; ++zz)
#pragma unroll
    for (int yy = 0; yy < 2; ++yy)
#pragma unroll
      for (int xx = 0; xx < 2; ++xx) {
        const int c = zz * 4 + yy * 2 + xx;
        coff[c] = ((zi[zz] * 128 + yi[yy]) * 128 + xi[xx]) * 128;   // bytes (32 ch * 4 B)
        cw[c]   = wzs[zz] * wys[yy] * wxs[xx];
      }
  const char* __restrict__ gbase = (const char*)grid;

  // ---- gather, channel-chunk-major: phase q loads chunk q of ALL 8 corners ----
  // (first phase issues 8 independent line-misses in parallel; later phases hit L1/MSHR)
#pragma unroll
  for (int qp = 0; qp < 4; ++qp) {
    s16x8 pk;
#pragma unroll
    for (int h = 0; h < 2; ++h) {
      const int q = qp * 2 + h;
      float4 v[8];
#pragma unroll
      for (int c = 0; c < 8; ++c)
        v[c] = *(const float4*)(gbase + coff[c] + q * 16);
      float f0 = 0.f, f1 = 0.f, f2 = 0.f, f3 = 0.f;
#pragma unroll
      for (int c = 0; c < 8; ++c) {
        f0 = fmaf(cw[c], v[c].x, f0);
        f1 = fmaf(cw[c], v[c].y, f1);
        f2 = fmaf(cw[c], v[c].z, f2);
        f3 = fmaf(cw[c], v[c].w, f3);
      }
      pk[h * 4 + 0] = (short)f2bf(f0);
      pk[h * 4 + 1] = (short)f2bf(f1);
      pk[h * 4 + 2] = (short)f2bf(f2);
      pk[h * 4 + 3] = (short)f2bf(f3);
    }
    *(s16x8*)&s_X[tid * XPAD + qp * 8] = pk;   // wave-local rows; no barrier needed
  }

  // ---- per-ray harmonic encoding @ Wr + br (f32, threads 0..127) ----
  // after the gather so the global loads issue at kernel entry
  if (tid < 128) {
    const int rr = tid >> 6, j = tid & 63;
    const int rg = blockIdx.x * 2 + rr;
    const float ddx = dirs[rg * 3 + 0], ddy = dirs[rg * 3 + 1], ddz = dirs[rg * 3 + 2];
    float h[21]; float f = 1.f;
#pragma unroll
    for (int q = 0; q < 3; ++q) {
      h[q * 3 + 0] = sinf(ddx * f); h[q * 3 + 1] = sinf(ddy * f); h[q * 3 + 2] = sinf(ddz * f);
      h[9 + q * 3 + 0] = cosf(ddx * f); h[9 + q * 3 + 1] = cosf(ddy * f); h[9 + q * 3 + 2] = cosf(ddz * f);
      f *= 2.f;
    }
    h[18] = ddx; h[19] = ddy; h[20] = ddz;
    float a = br[j];
#pragma unroll
    for (int i = 0; i < 21; ++i) a = fmaf(h[i], Wr[i * 64 + j], a);
    s_enc[rr][j] = a;
  }

  f32x4 acc[4][4];

  // ---- T1: 32 -> 64 (K=32, one k-step) ----
  {
    s16x8 a1[4];
#pragma unroll
    for (int mt = 0; mt < 4; ++mt)
      a1[mt] = *(const s16x8*)&s_X[(wrow + mt * 16 + ln15) * XPAD + quad * 8];
    float bv[4];
#pragma unroll
    for (int nt = 0; nt < 4; ++nt) bv[nt] = bt1[nt * 16 + ln15];
#pragma unroll
    for (int mt = 0; mt < 4; ++mt)
#pragma unroll
      for (int nt = 0; nt < 4; ++nt){ f32x4 c; c[0]=bv[nt];c[1]=bv[nt];c[2]=bv[nt];c[3]=bv[nt]; acc[mt][nt]=c; }
    s16x8 b[4];
#pragma unroll
    for (int nt = 0; nt < 4; ++nt)
      b[nt] = *(const s16x8*)(ws + (nt * 16 + ln15) * 32 + quad * 8);
#pragma unroll
    for (int mt = 0; mt < 4; ++mt)
#pragma unroll
      for (int nt = 0; nt < 4; ++nt)
        acc[mt][nt] = __builtin_amdgcn_mfma_f32_16x16x32_bf16(a1[mt], b[nt], acc[mt][nt], 0, 0, 0);
    store_relu(s_X, wrow, ln15, quad, acc);
  }

  // ---- T2: 64 -> 64 -> e ----
  {
    s16x8 a[4][2];
#pragma unroll
    for (int ks = 0; ks < 2; ++ks)
#pragma unroll
      for (int mt = 0; mt < 4; ++mt)
        a[mt][ks] = *(const s16x8*)&s_X[(wrow + mt * 16 + ln15) * XPAD + ks * 32 + quad * 8];
    layer64(a, ws + 2048, bt2, ln15, quad, acc);
    store_relu(s_X, wrow, ln15, quad, acc);   // X = e
  }

  // ---- keep e fragments in registers (A-operand layout) ----
  s16x8 ea[4][2];
#pragma unroll
  for (int ks = 0; ks < 2; ++ks)
#pragma unroll
    for (int mt = 0; mt < 4; ++mt)
      ea[mt][ks] = *(const s16x8*)&s_X[(wrow + mt * 16 + ln15) * XPAD + ks * 32 + quad * 8];

  // ---- opacity: relu(e@Wo1+bo1) -> X, then per-thread dot with Wo2 ----
  layer64(ea, ws + 6144, bo1, ln15, quad, acc);
  store_relu(s_X, wrow, ln15, quad, acc);
  float raw = bo2[0];
#pragma unroll
  for (int q = 0; q < 8; ++q) {
    s16x8 v = *(const s16x8*)&s_X[tid * XPAD + q * 8];
#pragma unroll
    for (int j = 0; j < 8; ++j)
      raw = fmaf(bf2f((unsigned short)v[j]), Wo2[q * 8 + j], raw);
  }
  const float density = softplusf_(raw);
  const float delta   = (fa - nr) * (1.0f / 128.0f);
  const float alpha   = 1.f - expf(-delta * density);

  __syncthreads();   // s_enc (cross-wave) ready

  // ---- color: cin-frags = e-frags + enc (enc varies only along k => per-wave broadcast frag) ----
  {
    s16x8 a[4][2];
#pragma unroll
    for (int ks = 0; ks < 2; ++ks) {
      const float* ep = &s_enc[r_loc][ks * 32 + quad * 8];
      float4 e0 = *(const float4*)ep;
      float4 e1 = *(const float4*)(ep + 4);
      float encv[8] = {e0.x, e0.y, e0.z, e0.w, e1.x, e1.y, e1.z, e1.w};
#pragma unroll
      for (int mt = 0; mt < 4; ++mt) {
        s16x8 v;
#pragma unroll
        for (int j = 0; j < 8; ++j)
          v[j] = (short)f2bf(bf2f((unsigned short)ea[mt][ks][j]) + encv[j]);
        a[mt][ks] = v;
      }
    }
    layer64(a, ws + 10240, bc1, ln15, quad, acc);
    store_relu(s_X, wrow, ln15, quad, acc);
  }
  float c0 = bc2[0], c1 = bc2[1], c2 = bc2[2];
#pragma unroll
  for (int q = 0; q < 8; ++q) {
    s16x8 v = *(const s16x8*)&s_X[tid * XPAD + q * 8];
#pragma unroll
    for (int j = 0; j < 8; ++j) {
      const float h = bf2f((unsigned short)v[j]);
      c0 = fmaf(h, Wc2[(q * 8 + j) * 3 + 0], c0);
      c1 = fmaf(h, Wc2[(q * 8 + j) * 3 + 1], c1);
      c2 = fmaf(h, Wc2[(q * 8 + j) * 3 + 2], c2);
    }
  }
  c0 = sigmoidf_(c0); c1 = sigmoidf_(c1); c2 = sigmoidf_(c2);

  // ---- transmittance: per-wave shfl scan (6 steps, no barriers) + cross-wave prefix ----
  float sc = 1.f - alpha;
#pragma unroll
  for (int off = 1; off < 64; off <<= 1) {
    const float u = __shfl_up(sc, off, 64);
    if (lane >= off) sc *= u;
  }
  float excl = __shfl_up(sc, 1, 64);
  if (lane == 0) excl = 1.f;
  if (lane == 63) s_wtot[wv] = sc;
  __syncthreads();
  const int w_in_ray = s_idx >> 6;                       // 0 or 1 within the ray
  const float prefix = w_in_ray ? s_wtot[r_loc * 2] : 1.f;
  const float wgt = prefix * excl * alpha;

  // ---- color integral ----
  float p0 = wgt * c0, p1 = wgt * c1, p2 = wgt * c2;
#pragma unroll
  for (int off = 32; off > 0; off >>= 1) {
    p0 += __shfl_down(p0, off, 64);
    p1 += __shfl_down(p1, off, 64);
    p2 += __shfl_down(p2, off, 64);
  }
  if (lane == 0) {
    s_part[r_loc][w_in_ray][0] = p0; s_part[r_loc][w_in_ray][1] = p1; s_part[r_loc][w_in_ray][2] = p2;
  }
  __syncthreads();
  if (s_idx == 0) {
    out[ray * 3 + 0] = s_part[r_loc][0][0] + s_part[r_loc][1][0];
    out[ray * 3 + 1] = s_part[r_loc][0][1] + s_part[r_loc][1][1];
    out[ray * 3 + 2] = s_part[r_loc][0][2] + s_part[r_loc][1][2];
    out[NRAYS * 3 + ray] = 1.f - s_wtot[r_loc * 2] * s_wtot[r_loc * 2 + 1];
  }
}

extern "C" void kernel_launch(void* const* d_in, const int* in_sizes, int n_in,
                              void* d_out, int out_size, void* d_ws, size_t ws_size,
                              hipStream_t stream)
{
  (void)in_sizes; (void)n_in; (void)out_size; (void)ws_size;
  const float* origins = (const float*)d_in[0];
  const float* dirs    = (const float*)d_in[1];
  const float* nearv   = (const float*)d_in[2];
  const float* farv    = (const float*)d_in[3];
  const float* grid    = (const float*)d_in[4];
  const float* Wr  = (const float*)d_in[5];
  const float* br  = (const float*)d_in[6];
  const float* Wt1 = (const float*)d_in[7];
  const float* bt1 = (const float*)d_in[8];
  const float* Wt2 = (const float*)d_in[9];
  const float* bt2 = (const float*)d_in[10];
  const float* Wo1 = (const float*)d_in[11];
  const float* bo1 = (const float*)d_in[12];
  const float* Wo2 = (const float*)d_in[13];
  const float* bo2 = (const float*)d_in[14];
  const float* Wc1 = (const float*)d_in[15];
  const float* bc1 = (const float*)d_in[16];
  const float* Wc2 = (const float*)d_in[17];
  const float* bc2 = (const float*)d_in[18];
  unsigned short* ws = (unsigned short*)d_ws;
  float* out = (float*)d_out;

  prep_weights<<<16, 256, 0, stream>>>(Wt1, Wt2, Wo1, Wc1, ws);
  lightplane_fwd<<<NRAYS / 2, 256, 0, stream>>>(origins, dirs, nearv, farv, grid,
                                                Wr, br, bt1, bt2, bo1, Wo2, bo2,
                                                bc1, Wc2, bc2, ws, out);
}

// Round 5
// 507.397 us; speedup vs baseline: 1.1096x; 1.0057x over previous
//
#include <hip/hip_runtime.h>
#include <math.h>

#define NRAYS 8192
#define XPAD 72   // bf16 per LDS activation row: 64 + 8 pad (144 B, 16B-aligned rows)

typedef short s16x8 __attribute__((ext_vector_type(8)));
typedef float f32x4 __attribute__((ext_vector_type(4)));

__device__ __forceinline__ unsigned short f2bf(float x){
  unsigned u = __float_as_uint(x);
  u += 0x7FFF + ((u >> 16) & 1);           // RNE
  return (unsigned short)(u >> 16);
}
__device__ __forceinline__ float bf2f(unsigned short s){ return __uint_as_float(((unsigned)s) << 16); }
__device__ __forceinline__ float softplusf_(float x){ return (x > 20.f) ? x : log1pf(expf(x)); }
__device__ __forceinline__ float sigmoidf_(float x){ return 1.f / (1.f + expf(-x)); }

// d_ws layout (ushort elements): WT1[64][32] @0, WT2[64][64] @2048, WO1[64][64] @6144, WC1[64][64] @10240
__global__ void prep_weights(const float* __restrict__ Wt1, const float* __restrict__ Wt2,
                             const float* __restrict__ Wo1, const float* __restrict__ Wc1,
                             unsigned short* __restrict__ ws)
{
  const int i0 = blockIdx.x * blockDim.x + threadIdx.x;
  const int st = gridDim.x * blockDim.x;
  for (int i = i0; i < 2048; i += st){ int n = i >> 5, k = i & 31; ws[i]         = f2bf(Wt1[k * 64 + n]); }
  for (int i = i0; i < 4096; i += st){ int n = i >> 6, k = i & 63; ws[2048 + i]  = f2bf(Wt2[k * 64 + n]); }
  for (int i = i0; i < 4096; i += st){ int n = i >> 6, k = i & 63; ws[6144 + i]  = f2bf(Wo1[k * 64 + n]); }
  for (int i = i0; i < 4096; i += st){ int n = i >> 6, k = i & 63; ws[10240 + i] = f2bf(Wc1[k * 64 + n]); }
}

// K=64 layer, N-HALF nh (32 cols): acc[mt][nt] = bias + A @ W-half.
// Halving the accumulator (32 regs instead of 64) is what lets 4 waves/SIMD fit in 128 regs.
__device__ __forceinline__ void layer64_half(const s16x8 a[4][2], const unsigned short* __restrict__ wt,
                                             const float* __restrict__ bias, int ln15, int quad, int nh,
                                             f32x4 acc[4][2])
{
  float bv[2];
#pragma unroll
  for (int nt = 0; nt < 2; ++nt) bv[nt] = bias[nh * 32 + nt * 16 + ln15];
#pragma unroll
  for (int mt = 0; mt < 4; ++mt)
#pragma unroll
    for (int nt = 0; nt < 2; ++nt){ f32x4 c; c[0]=bv[nt];c[1]=bv[nt];c[2]=bv[nt];c[3]=bv[nt]; acc[mt][nt]=c; }
#pragma unroll
  for (int ks = 0; ks < 2; ++ks){
    s16x8 b[2];
#pragma unroll
    for (int nt = 0; nt < 2; ++nt)
      b[nt] = *(const s16x8*)(wt + (nh * 32 + nt * 16 + ln15) * 64 + ks * 32 + quad * 8);
#pragma unroll
    for (int mt = 0; mt < 4; ++mt)
#pragma unroll
      for (int nt = 0; nt < 2; ++nt)
        acc[mt][nt] = __builtin_amdgcn_mfma_f32_16x16x32_bf16(a[mt][ks], b[nt], acc[mt][nt], 0, 0, 0);
  }
}

// relu + bf16 + scatter one N-half back to X rows (wave-local rows)
__device__ __forceinline__ void store_relu_half(unsigned short* __restrict__ sX, int wrow, int ln15,
                                                int quad, int nh, const f32x4 acc[4][2])
{
#pragma unroll
  for (int mt = 0; mt < 4; ++mt){
    const int rowb = wrow + mt * 16 + quad * 4;
#pragma unroll
    for (int nt = 0; nt < 2; ++nt){
      const int col = nh * 32 + nt * 16 + ln15;
#pragma unroll
      for (int r = 0; r < 4; ++r)
        sX[(rowb + r) * XPAD + col] = f2bf(fmaxf(acc[mt][nt][r], 0.f));
    }
  }
}

// (256,4): 4 waves/SIMD needs <=128 unified regs/wave. Accumulator halved to acc[4][2] (32)
// + ~90 arch VGPRs fits. R1-R3 spilled here because the full 64-reg acc blew the budget
// (WRITE_SIZE 151-174 MB of scratch on a kernel that writes 130 KB). Watch WRITE_SIZE.
extern "C" __global__ __launch_bounds__(256, 4)
void lightplane_fwd(const float* __restrict__ origins, const float* __restrict__ dirs,
                    const float* __restrict__ nearv,   const float* __restrict__ farv,
                    const float* __restrict__ grid,
                    const float* __restrict__ Wr,  const float* __restrict__ br,
                    const float* __restrict__ bt1, const float* __restrict__ bt2,
                    const float* __restrict__ bo1,
                    const float* __restrict__ Wo2, const float* __restrict__ bo2,
                    const float* __restrict__ bc1,
                    const float* __restrict__ Wc2, const float* __restrict__ bc2,
                    const unsigned short* __restrict__ ws,
                    float* __restrict__ out)
{
  __shared__ unsigned short s_X[256 * XPAD];   // 36864 B
  __shared__ float s_enc[2][64];
  __shared__ float s_part[2][2][4];
  __shared__ float s_wtot[4];

  const int tid   = threadIdx.x;
  const int lane  = tid & 63;
  const int wv    = tid >> 6;
  const int ln15  = lane & 15, quad = lane >> 4;
  const int wrow  = wv * 64;
  const int r_loc = tid >> 7;
  const int s_idx = tid & 127;
  const int ray   = blockIdx.x * 2 + r_loc;   // input ray order: best HBM channel spread

  // ---- sample point ----
  const float dx = dirs[ray * 3 + 0], dy = dirs[ray * 3 + 1], dz = dirs[ray * 3 + 2];
  const float ox = origins[ray * 3 + 0], oy = origins[ray * 3 + 1], oz = origins[ray * 3 + 2];
  const float nr = nearv[ray], fa = farv[ray];
  const float t  = nr + (fa - nr) * ((s_idx + 0.5f) * (1.0f / 128.0f));
  const float px = fmaf(t, dx, ox), py = fmaf(t, dy, oy), pz = fmaf(t, dz, oz);

  const float cx = (px + 1.f) * 63.5f, cy = (py + 1.f) * 63.5f, cz = (pz + 1.f) * 63.5f;
  const float fx0 = floorf(cx), fy0 = floorf(cy), fz0 = floorf(cz);
  const float frx = cx - fx0, fry = cy - fy0, frz = cz - fz0;
  int ix0 = min(max((int)fx0, 0), 127), iy0 = min(max((int)fy0, 0), 127), iz0 = min(max((int)fz0, 0), 127);
  int ix1 = min(ix0 + 1, 127), iy1 = min(iy0 + 1, 127), iz1 = min(iz0 + 1, 127);
  const float wxs[2] = {1.f - frx, frx}, wys[2] = {1.f - fry, fry}, wzs[2] = {1.f - frz, frz};
  const int xi[2] = {ix0, ix1}, yi[2] = {iy0, iy1}, zi[2] = {iz0, iz1};

  float fe[32];
#pragma unroll
  for (int k = 0; k < 32; ++k) fe[k] = 0.f;

  // ---- gather, corner-major (R0 structure, fastest measured): per (z,y) pair stream
  // 2 x-adjacent corners (2 lines/thread in flight, consumed immediately -> no L2 blowup)
  const float4* __restrict__ gb = (const float4*)grid;
#pragma unroll
  for (int zz = 0; zz < 2; ++zz)
#pragma unroll
    for (int yy = 0; yy < 2; ++yy) {
      const size_t rowb = (size_t)((zi[zz] * 128 + yi[yy]) * 128) * 8;
      const float4* p0 = gb + rowb + (size_t)xi[0] * 8;
      const float4* p1 = gb + rowb + (size_t)xi[1] * 8;
      float4 v0[8], v1[8];
#pragma unroll
      for (int q = 0; q < 8; ++q) { v0[q] = p0[q]; v1[q] = p1[q]; }
      const float wzy = wzs[zz] * wys[yy];
      const float wA = wzy * wxs[0], wB = wzy * wxs[1];
#pragma unroll
      for (int q = 0; q < 8; ++q) {
        fe[q * 4 + 0] = fmaf(wA, v0[q].x, fmaf(wB, v1[q].x, fe[q * 4 + 0]));
        fe[q * 4 + 1] = fmaf(wA, v0[q].y, fmaf(wB, v1[q].y, fe[q * 4 + 1]));
        fe[q * 4 + 2] = fmaf(wA, v0[q].z, fmaf(wB, v1[q].z, fe[q * 4 + 2]));
        fe[q * 4 + 3] = fmaf(wA, v0[q].w, fmaf(wB, v1[q].w, fe[q * 4 + 3]));
      }
    }

  // feats -> bf16 -> X[t][0..31]  (wave-local rows; no barrier needed)
#pragma unroll
  for (int q = 0; q < 4; ++q) {
    s16x8 v;
#pragma unroll
    for (int j = 0; j < 8; ++j) v[j] = (short)f2bf(fe[q * 8 + j]);
    *(s16x8*)&s_X[tid * XPAD + q * 8] = v;
  }

  // ---- per-ray harmonic encoding @ Wr + br (f32, threads 0..127) ----
  if (tid < 128) {
    const int rr = tid >> 6, j = tid & 63;
    const int rg = blockIdx.x * 2 + rr;
    const float ddx = dirs[rg * 3 + 0], ddy = dirs[rg * 3 + 1], ddz = dirs[rg * 3 + 2];
    float h[21]; float f = 1.f;
#pragma unroll
    for (int q = 0; q < 3; ++q) {
      h[q * 3 + 0] = sinf(ddx * f); h[q * 3 + 1] = sinf(ddy * f); h[q * 3 + 2] = sinf(ddz * f);
      h[9 + q * 3 + 0] = cosf(ddx * f); h[9 + q * 3 + 1] = cosf(ddy * f); h[9 + q * 3 + 2] = cosf(ddz * f);
      f *= 2.f;
    }
    h[18] = ddx; h[19] = ddy; h[20] = ddz;
    float a = br[j];
#pragma unroll
    for (int i = 0; i < 21; ++i) a = fmaf(h[i], Wr[i * 64 + j], a);
    s_enc[rr][j] = a;
  }

  f32x4 acc[4][2];

  // ---- T1: 32 -> 64 (K=32), two N-halves ----
  {
    s16x8 a1[4];
#pragma unroll
    for (int mt = 0; mt < 4; ++mt)
      a1[mt] = *(const s16x8*)&s_X[(wrow + mt * 16 + ln15) * XPAD + quad * 8];
#pragma unroll
    for (int nh = 0; nh < 2; ++nh) {
      float bv[2];
#pragma unroll
      for (int nt = 0; nt < 2; ++nt) bv[nt] = bt1[nh * 32 + nt * 16 + ln15];
#pragma unroll
      for (int mt = 0; mt < 4; ++mt)
#pragma unroll
        for (int nt = 0; nt < 2; ++nt){ f32x4 c; c[0]=bv[nt];c[1]=bv[nt];c[2]=bv[nt];c[3]=bv[nt]; acc[mt][nt]=c; }
      s16x8 b[2];
#pragma unroll
      for (int nt = 0; nt < 2; ++nt)
        b[nt] = *(const s16x8*)(ws + (nh * 32 + nt * 16 + ln15) * 32 + quad * 8);
#pragma unroll
      for (int mt = 0; mt < 4; ++mt)
#pragma unroll
        for (int nt = 0; nt < 2; ++nt)
          acc[mt][nt] = __builtin_amdgcn_mfma_f32_16x16x32_bf16(a1[mt], b[nt], acc[mt][nt], 0, 0, 0);
      store_relu_half(s_X, wrow, ln15, quad, nh, acc);
    }
  }

  // ---- T2: 64 -> 64 -> e (two N-halves; input frags read once) ----
  {
    s16x8 a[4][2];
#pragma unroll
    for (int ks = 0; ks < 2; ++ks)
#pragma unroll
      for (int mt = 0; mt < 4; ++mt)
        a[mt][ks] = *(const s16x8*)&s_X[(wrow + mt * 16 + ln15) * XPAD + ks * 32 + quad * 8];
#pragma unroll
    for (int nh = 0; nh < 2; ++nh) {
      layer64_half(a, ws + 2048, bt2, ln15, quad, nh, acc);
      store_relu_half(s_X, wrow, ln15, quad, nh, acc);   // X = e
    }
  }

  // ---- keep e fragments in registers (A-operand layout) ----
  s16x8 ea[4][2];
#pragma unroll
  for (int ks = 0; ks < 2; ++ks)
#pragma unroll
    for (int mt = 0; mt < 4; ++mt)
      ea[mt][ks] = *(const s16x8*)&s_X[(wrow + mt * 16 + ln15) * XPAD + ks * 32 + quad * 8];

  // ---- opacity: relu(e@Wo1+bo1) -> X, then per-thread dot with Wo2 ----
#pragma unroll
  for (int nh = 0; nh < 2; ++nh) {
    layer64_half(ea, ws + 6144, bo1, ln15, quad, nh, acc);
    store_relu_half(s_X, wrow, ln15, quad, nh, acc);
  }
  float raw = bo2[0];
#pragma unroll
  for (int q = 0; q < 8; ++q) {
    s16x8 v = *(const s16x8*)&s_X[tid * XPAD + q * 8];
#pragma unroll
    for (int j = 0; j < 8; ++j)
      raw = fmaf(bf2f((unsigned short)v[j]), Wo2[q * 8 + j], raw);
  }
  const float density = softplusf_(raw);
  const float delta   = (fa - nr) * (1.0f / 128.0f);
  const float alpha   = 1.f - expf(-delta * density);

  __syncthreads();   // s_enc (cross-wave) ready

  // ---- color: cin = e + enc; frags rebuilt per (half, ks) to cap live registers ----
  {
    float encv[2][8];
#pragma unroll
    for (int ks = 0; ks < 2; ++ks) {
      const float* ep = &s_enc[r_loc][ks * 32 + quad * 8];
      float4 e0 = *(const float4*)ep;
      float4 e1 = *(const float4*)(ep + 4);
      encv[ks][0]=e0.x; encv[ks][1]=e0.y; encv[ks][2]=e0.z; encv[ks][3]=e0.w;
      encv[ks][4]=e1.x; encv[ks][5]=e1.y; encv[ks][6]=e1.z; encv[ks][7]=e1.w;
    }
#pragma unroll
    for (int nh = 0; nh < 2; ++nh) {
      float bv[2];
#pragma unroll
      for (int nt = 0; nt < 2; ++nt) bv[nt] = bc1[nh * 32 + nt * 16 + ln15];
#pragma unroll
      for (int mt = 0; mt < 4; ++mt)
#pragma unroll
        for (int nt = 0; nt < 2; ++nt){ f32x4 c; c[0]=bv[nt];c[1]=bv[nt];c[2]=bv[nt];c[3]=bv[nt]; acc[mt][nt]=c; }
#pragma unroll
      for (int ks = 0; ks < 2; ++ks) {
        s16x8 b[2];
#pragma unroll
        for (int nt = 0; nt < 2; ++nt)
          b[nt] = *(const s16x8*)(ws + 10240 + (nh * 32 + nt * 16 + ln15) * 64 + ks * 32 + quad * 8);
#pragma unroll
        for (int mt = 0; mt < 4; ++mt) {
          s16x8 ca;
#pragma unroll
          for (int j = 0; j < 8; ++j)
            ca[j] = (short)f2bf(bf2f((unsigned short)ea[mt][ks][j]) + encv[ks][j]);
#pragma unroll
          for (int nt = 0; nt < 2; ++nt)
            acc[mt][nt] = __builtin_amdgcn_mfma_f32_16x16x32_bf16(ca, b[nt], acc[mt][nt], 0, 0, 0);
        }
      }
      store_relu_half(s_X, wrow, ln15, quad, nh, acc);
    }
  }
  float c0 = bc2[0], c1 = bc2[1], c2 = bc2[2];
#pragma unroll
  for (int q = 0; q < 8; ++q) {
    s16x8 v = *(const s16x8*)&s_X[tid * XPAD + q * 8];
#pragma unroll
    for (int j = 0; j < 8; ++j) {
      const float h = bf2f((unsigned short)v[j]);
      c0 = fmaf(h, Wc2[(q * 8 + j) * 3 + 0], c0);
      c1 = fmaf(h, Wc2[(q * 8 + j) * 3 + 1], c1);
      c2 = fmaf(h, Wc2[(q * 8 + j) * 3 + 2], c2);
    }
  }
  c0 = sigmoidf_(c0); c1 = sigmoidf_(c1); c2 = sigmoidf_(c2);

  // ---- transmittance: per-wave shfl scan (6 steps, no barriers) + cross-wave prefix ----
  float sc = 1.f - alpha;
#pragma unroll
  for (int off = 1; off < 64; off <<= 1) {
    const float u = __shfl_up(sc, off, 64);
    if (lane >= off) sc *= u;
  }
  float excl = __shfl_up(sc, 1, 64);
  if (lane == 0) excl = 1.f;
  if (lane == 63) s_wtot[wv] = sc;
  __syncthreads();
  const int w_in_ray = s_idx >> 6;                       // 0 or 1 within the ray
  const float prefix = w_in_ray ? s_wtot[r_loc * 2] : 1.f;
  const float wgt = prefix * excl * alpha;

  // ---- color integral ----
  float p0 = wgt * c0, p1 = wgt * c1, p2 = wgt * c2;
#pragma unroll
  for (int off = 32; off > 0; off >>= 1) {
    p0 += __shfl_down(p0, off, 64);
    p1 += __shfl_down(p1, off, 64);
    p2 += __shfl_down(p2, off, 64);
  }
  if (lane == 0) {
    s_part[r_loc][w_in_ray][0] = p0; s_part[r_loc][w_in_ray][1] = p1; s_part[r_loc][w_in_ray][2] = p2;
  }
  __syncthreads();
  if (s_idx == 0) {
    out[ray * 3 + 0] = s_part[r_loc][0][0] + s_part[r_loc][1][0];
    out[ray * 3 + 1] = s_part[r_loc][0][1] + s_part[r_loc][1][1];
    out[ray * 3 + 2] = s_part[r_loc][0][2] + s_part[r_loc][1][2];
    out[NRAYS * 3 + ray] = 1.f - s_wtot[r_loc * 2] * s_wtot[r_loc * 2 + 1];
  }
}

extern "C" void kernel_launch(void* const* d_in, const int* in_sizes, int n_in,
                              void* d_out, int out_size, void* d_ws, size_t ws_size,
                              hipStream_t stream)
{
  (void)in_sizes; (void)n_in; (void)out_size; (void)ws_size;
  const float* origins = (const float*)d_in[0];
  const float* dirs    = (const float*)d_in[1];
  const float* nearv   = (const float*)d_in[2];
  const float* farv    = (const float*)d_in[3];
  const float* grid    = (const float*)d_in[4];
  const float* Wr  = (const float*)d_in[5];
  const float* br  = (const float*)d_in[6];
  const float* Wt1 = (const float*)d_in[7];
  const float* bt1 = (const float*)d_in[8];
  const float* Wt2 = (const float*)d_in[9];
  const float* bt2 = (const float*)d_in[10];
  const float* Wo1 = (const float*)d_in[11];
  const float* bo1 = (const float*)d_in[12];
  const float* Wo2 = (const float*)d_in[13];
  const float* bo2 = (const float*)d_in[14];
  const float* Wc1 = (const float*)d_in[15];
  const float* bc1 = (const float*)d_in[16];
  const float* Wc2 = (const float*)d_in[17];
  const float* bc2 = (const float*)d_in[18];
  unsigned short* ws = (unsigned short*)d_ws;
  float* out = (float*)d_out;

  prep_weights<<<16, 256, 0, stream>>>(Wt1, Wt2, Wo1, Wc1, ws);
  lightplane_fwd<<<NRAYS / 2, 256, 0, stream>>>(origins, dirs, nearv, farv, grid,
                                                Wr, br, bt1, bt2, bo1, Wo2, bo2,
                                                bc1, Wc2, bc2, ws, out);
}